// Round 1
// baseline (286.518 us; speedup 1.0000x reference)
//
#include <hip/hip_runtime.h>
#include <hip/hip_cooperative_groups.h>
#include <math.h>

// NetVLAD clustering layer, f32, MI355X — single cooperative kernel.
// x:[16,256,1500], centroids:[64,256], lin_w:[66,256], lin_b:[66]
// out: [16, 64*256] f32
//
// Phase 1 (block=(chunk,u)): stage x chunk to LDS once; logits (4-wave
//   f-split + LDS tree reduce, 64t + 32t passes); softmax -> a in LDS only;
//   8x8 VALU aggregation from LDS (asum folded into the k-loop).
// grid.sync()
// Phase 2: reduce 16 chunk-partials, subtract asum*centroid, intra-norm.
// grid.sync()
// Phase 3: global L2 normalize (float4).

namespace cg = cooperative_groups;

#define NU 16
#define NF 256
#define NT 1500
#define NC 64
#define NCG 66          // clusters + ghosts
#define EPSN 1e-12f
#define TCH 96          // t-chunk per block (16 chunks cover 1536 >= 1500)
#define NCHUNK 16
#define XPAD 97         // LDS row stride: 97 % 32 == 1 -> conflict-free columns

__device__ __forceinline__ float blk_reduce_sum(float v, float* sbuf) {
    #pragma unroll
    for (int off = 32; off > 0; off >>= 1) v += __shfl_down(v, off, 64);
    const int lane = threadIdx.x & 63, wv = threadIdx.x >> 6;
    if (lane == 0) sbuf[wv] = v;
    __syncthreads();
    float r = sbuf[0] + sbuf[1] + sbuf[2] + sbuf[3];
    __syncthreads();
    return r;
}

// One logits pass over 64 lane-mapped t's (kbase..kbase+63 within the chunk).
// Stores a[c][kbase+lane] for lane < nstore (zeros for t >= NT).
// scratch (8448 f) is time-shared: wsm[4][66][16] during accumulation,
// red[2][66][64] during the cross-wave reduce.
__device__ __forceinline__ void logits_pass(
        const float* __restrict__ lin_w, const float* __restrict__ lin_b,
        const float (*Xsm)[XPAD], float (*Asm)[XPAD], float* scratch,
        const int wave, const int lane, const int kbase, const int nstore,
        const int t0) {
    float acc[NCG];
    #pragma unroll
    for (int c = 0; c < NCG; ++c) acc[c] = 0.0f;

    const int kk = min(kbase + lane, TCH - 1);   // clamped LDS column (finite data)
    float (*wsm)[NCG][16] = (float (*)[NCG][16])scratch;

    for (int fc = 0; fc < 4; ++fc) {
        const int fbase = wave * 64 + fc * 16;
        for (int idx = lane; idx < NCG * 16; idx += 64) {
            const int c = idx >> 4, k = idx & 15;
            wsm[wave][c][k] = lin_w[c * NF + fbase + k];
        }
        __syncthreads();
        float xv[16];
        #pragma unroll
        for (int k = 0; k < 16; ++k) xv[k] = Xsm[fbase + k][kk];
        #pragma unroll
        for (int c = 0; c < NCG; ++c) {
            const float4* wr = (const float4*)(&wsm[wave][c][0]);  // 64B-aligned
            const float4 w0 = wr[0], w1 = wr[1], w2 = wr[2], w3 = wr[3];
            acc[c] += w0.x*xv[0]  + w0.y*xv[1]  + w0.z*xv[2]  + w0.w*xv[3]
                    + w1.x*xv[4]  + w1.y*xv[5]  + w1.z*xv[6]  + w1.w*xv[7]
                    + w2.x*xv[8]  + w2.y*xv[9]  + w2.z*xv[10] + w2.w*xv[11]
                    + w3.x*xv[12] + w3.y*xv[13] + w3.z*xv[14] + w3.w*xv[15];
        }
        __syncthreads();
    }

    float (*red)[NCG][64] = (float (*)[NCG][64])scratch;
    if (wave >= 2) {
        #pragma unroll
        for (int c = 0; c < NCG; ++c) red[wave - 2][c][lane] = acc[c];
    }
    __syncthreads();
    if (wave < 2) {
        #pragma unroll
        for (int c = 0; c < NCG; ++c) acc[c] += red[wave][c][lane];
    }
    __syncthreads();
    if (wave == 1) {
        #pragma unroll
        for (int c = 0; c < NCG; ++c) red[0][c][lane] = acc[c];
    }
    __syncthreads();
    if (wave == 0) {
        #pragma unroll
        for (int c = 0; c < NCG; ++c) acc[c] += red[0][c][lane] + lin_b[c];
        float m = -INFINITY;
        #pragma unroll
        for (int c = 0; c < NCG; ++c) m = fmaxf(m, acc[c]);
        float s = 0.0f;
        #pragma unroll
        for (int c = 0; c < NCG; ++c) { acc[c] = __expf(acc[c] - m); s += acc[c]; }
        const int t = t0 + kbase + lane;
        const float scale = (t < NT) ? (1.0f / s) : 0.0f;   // zero padded t's
        if (lane < nstore) {
            #pragma unroll
            for (int c = 0; c < NC; ++c) Asm[c][kbase + lane] = acc[c] * scale;
        }
    }
    __syncthreads();
}

__global__ __launch_bounds__(256, 1) void fused_netvlad(
        const float* __restrict__ x, const float* __restrict__ centroids,
        const float* __restrict__ lin_w, const float* __restrict__ lin_b,
        float* __restrict__ partial, float* __restrict__ asum_part,
        float* __restrict__ compn, float* __restrict__ rowsq,
        float* __restrict__ out) {
    // 154.3 KiB total -> exactly 1 block/CU, 256 blocks co-resident.
    __shared__ float Xsm[NF][XPAD];          // 24832 f
    __shared__ float Asm[NC][XPAD];          //  6208 f
    __shared__ float scratch[2 * NCG * 64];  //  8448 f (wsm / red time-shared)
    __shared__ float sbuf[4];

    cg::grid_group grid = cg::this_grid();

    const int chunk = blockIdx.x, u = blockIdx.y;
    const int tid  = threadIdx.x;
    const int lane = tid & 63, wave = tid >> 6;
    const int t0 = chunk * TCH;

    // ---------------- Phase 1a: stage x chunk -> LDS (zero-fill tail) -------
    {
        const int cs = tid >> 2;            // f row 0..63 (+64r)
        const int ks = (tid & 3) * 4;       // t offset 0/4/8/12
        #pragma unroll
        for (int k0 = 0; k0 < TCH; k0 += 16) {
            #pragma unroll
            for (int r = 0; r < 4; ++r) {
                const int f  = cs + 64 * r;
                const int kk = k0 + ks;
                const int tg = t0 + kk;
                const float* rp = x + ((size_t)(u * NF + f)) * NT + tg;
                float4 v;
                if (tg + 3 < NT) v = *(const float4*)rp;   // 16B-aligned: 6000|t0*4|16
                else {
                    v.x = (tg + 0 < NT) ? rp[0] : 0.0f;
                    v.y = (tg + 1 < NT) ? rp[1] : 0.0f;
                    v.z = (tg + 2 < NT) ? rp[2] : 0.0f;
                    v.w = (tg + 3 < NT) ? rp[3] : 0.0f;
                }
                Xsm[f][kk+0] = v.x; Xsm[f][kk+1] = v.y;
                Xsm[f][kk+2] = v.z; Xsm[f][kk+3] = v.w;
            }
        }
    }
    __syncthreads();

    // ---------------- Phase 1b: logits + softmax (a lives only in LDS) -----
    logits_pass(lin_w, lin_b, Xsm, Asm, scratch, wave, lane, 0, 64, t0);
    logits_pass(lin_w, lin_b, Xsm, Asm, scratch, wave, lane, 64, 32, t0);

    // ---------------- Phase 1c: 8x8 aggregation over full chunk ------------
    {
        float aggacc[8][8];
        float asacc[8];
        #pragma unroll
        for (int i = 0; i < 8; ++i) {
            asacc[i] = 0.0f;
            #pragma unroll
            for (int j = 0; j < 8; ++j) aggacc[i][j] = 0.0f;
        }
        const int c_base = (tid >> 5) * 8;   // 8 groups x 8 c = 64 c
        const int fl = tid & 31;             // f = fl + 32j

        #pragma unroll 4
        for (int k = 0; k < TCH; ++k) {
            float av[8], xv[8];
            #pragma unroll
            for (int i = 0; i < 8; ++i) av[i] = Asm[c_base + i][k];   // broadcast
            #pragma unroll
            for (int j = 0; j < 8; ++j) xv[j] = Xsm[fl + 32 * j][k];  // stride 97: conflict-free
            #pragma unroll
            for (int i = 0; i < 8; ++i) {
                asacc[i] += av[i];                                    // asum folded in
                #pragma unroll
                for (int j = 0; j < 8; ++j) aggacc[i][j] += av[i] * xv[j];
            }
        }

        #pragma unroll
        for (int i = 0; i < 8; ++i) {
            float* op = partial + ((size_t)((chunk * NU + u) * NC + c_base + i)) * NF;
            #pragma unroll
            for (int j = 0; j < 8; ++j) op[fl + 32 * j] = aggacc[i][j];
        }
        if (fl == 0) {
            #pragma unroll
            for (int i = 0; i < 8; ++i)
                asum_part[(chunk * NU + u) * NC + c_base + i] = asacc[i];
        }
    }

    __threadfence();
    grid.sync();

    // ---------------- Phase 2: reduce partials + intra-normalize -----------
    const int B = blockIdx.y * gridDim.x + blockIdx.x;   // 0..255
    for (int task = 0; task < 4; ++task) {
        const int tix = B * 4 + task;        // 0..1023
        const int uu = tix >> 6, cc = tix & 63;

        float asum = 0.0f;                   // uniform -> scalar loads
        #pragma unroll
        for (int ch = 0; ch < NCHUNK; ++ch)
            asum += asum_part[(ch * NU + uu) * NC + cc];

        float val = 0.0f;
        #pragma unroll
        for (int ch = 0; ch < NCHUNK; ++ch)
            val += partial[((size_t)((ch * NU + uu) * NC + cc)) * NF + tid];
        val -= asum * centroids[cc * NF + tid];

        const float ss = blk_reduce_sum(val * val, sbuf);
        const float d  = fmaxf(sqrtf(ss), EPSN);
        compn[((size_t)(uu * NC + cc)) * NF + tid] = val / d;
        if (tid == 0) rowsq[uu * NC + cc] = ss / (d * d);
    }

    __threadfence();
    grid.sync();

    // ---------------- Phase 3: global L2 normalize -------------------------
    {
        const int uu = B >> 4, sl = B & 15;
        float gss = 0.0f;                    // uniform -> scalar loads
        #pragma unroll
        for (int c2 = 0; c2 < NC; ++c2) gss += rowsq[uu * NC + c2];
        const float inv = 1.0f / fmaxf(sqrtf(gss), EPSN);
        const int base = uu * (NC * NF) + sl * 1024 + tid * 4;
        float4 v = *(const float4*)(compn + base);
        v.x *= inv; v.y *= inv; v.z *= inv; v.w *= inv;
        *(float4*)(out + base) = v;
    }
}

// ---------------- launcher ----------------
extern "C" void kernel_launch(void* const* d_in, const int* in_sizes, int n_in,
                              void* d_out, int out_size, void* d_ws, size_t ws_size,
                              hipStream_t stream) {
    (void)in_sizes; (void)n_in; (void)out_size; (void)ws_size;
    const float* x         = (const float*)d_in[0];
    const float* centroids = (const float*)d_in[1];
    const float* lin_w     = (const float*)d_in[2];
    const float* lin_b     = (const float*)d_in[3];
    float* out = (float*)d_out;

    float* ws        = (float*)d_ws;
    float* partial   = ws;                                    // 16*16*64*256 = 4,194,304 f
    float* asum_part = partial + (size_t)NCHUNK * NU * NC * NF; // 16*16*64 = 16,384 f
    float* compn     = asum_part + NCHUNK * NU * NC;          // 262,144 f
    float* rowsq     = compn + NU * NC * NF;                  // 1,024 f  (~17.9 MB total)

    void* args[] = {(void*)&x, (void*)&centroids, (void*)&lin_w, (void*)&lin_b,
                    (void*)&partial, (void*)&asum_part, (void*)&compn,
                    (void*)&rowsq, (void*)&out};
    hipLaunchCooperativeKernel((const void*)fused_netvlad,
                               dim3(NCHUNK, NU), dim3(256), args, 0, stream);
}

// Round 2
// 135.605 us; speedup vs baseline: 2.1129x; 2.1129x over previous
//
#include <hip/hip_runtime.h>
#include <math.h>

// NetVLAD clustering layer, f32, MI355X — 3 ordinary kernels (no cooperative).
// x:[16,256,1500], centroids:[64,256], lin_w:[66,256], lin_b:[66]
// out: [16, 64*256] f32
//
// KA (chunk,u): stage x chunk (48 t) -> LDS; logits (4-wave f-split, 3-round
//     LDS reduce); softmax -> a in LDS only; 8x8 aggregation + folded asum.
//     79.6 KB LDS -> 2 blocks/CU -> 8 waves/CU.
// KB (c,u): reduce 32 chunk-partials, subtract asum*centroid, intra-norm.
// KC: global L2 scale (float4).

#define NU 16
#define NF 256
#define NT 1500
#define NC 64
#define NCG 66          // clusters + ghosts
#define EPSN 1e-12f
#define TCH 48          // t-chunk (32 chunks cover 1536 >= 1500)
#define NCHUNK 32
#define XP 49           // LDS row stride: 49 % 32 = 17, gcd(17,32)=1 -> conflict-free

__device__ __forceinline__ float blk_reduce_sum(float v, float* sbuf) {
    #pragma unroll
    for (int off = 32; off > 0; off >>= 1) v += __shfl_down(v, off, 64);
    const int lane = threadIdx.x & 63, wv = threadIdx.x >> 6;
    if (lane == 0) sbuf[wv] = v;
    __syncthreads();
    float r = sbuf[0] + sbuf[1] + sbuf[2] + sbuf[3];
    __syncthreads();
    return r;
}

// ---------------- KA: logits + softmax + per-chunk aggregation ----------------
__global__ __launch_bounds__(256, 2) void ka_fused(
        const float* __restrict__ x, const float* __restrict__ lin_w,
        const float* __restrict__ lin_b, float* __restrict__ partial,
        float* __restrict__ asum_part) {
    __shared__ float Xsm[NF][XP];        // 50176 B
    __shared__ float Asm[NC][XP];        // 12544 B
    __shared__ float scratch[NCG * 64];  // 16896 B: wsm[4][66][16] / red[66][64]
    // total 79616 B -> 2 blocks/CU

    const int chunk = blockIdx.x, u = blockIdx.y;
    const int tid = threadIdx.x, lane = tid & 63, wave = tid >> 6;
    const int t0 = chunk * TCH;

    // ---- stage X chunk -> LDS (zero-fill past NT) ----
    {
        const int fr = tid >> 2;          // f row 0..63 (+64r)
        const int ks = (tid & 3) * 4;     // t offset 0,4,8,12
        #pragma unroll
        for (int r = 0; r < 4; ++r) {
            const int f = fr + 64 * r;
            const float* rp = x + (size_t)(u * NF + f) * NT + t0;
            #pragma unroll
            for (int q = 0; q < 3; ++q) {
                const int kk = ks + 16 * q;
                const int tg = t0 + kk;
                float4 v;
                if (tg + 3 < NT) v = *(const float4*)(rp + kk);  // 16B-aligned
                else {
                    v.x = (tg + 0 < NT) ? rp[kk + 0] : 0.0f;
                    v.y = (tg + 1 < NT) ? rp[kk + 1] : 0.0f;
                    v.z = (tg + 2 < NT) ? rp[kk + 2] : 0.0f;
                    v.w = (tg + 3 < NT) ? rp[kk + 3] : 0.0f;
                }
                Xsm[f][kk + 0] = v.x; Xsm[f][kk + 1] = v.y;
                Xsm[f][kk + 2] = v.z; Xsm[f][kk + 3] = v.w;
            }
        }
    }
    __syncthreads();

    // ---- logits: wave w accumulates f-quarter [64w, 64w+64) for 48 t's ----
    float acc[NCG];
    #pragma unroll
    for (int c = 0; c < NCG; ++c) acc[c] = 0.0f;
    {
        const int kk = (lane < TCH) ? lane : (TCH - 1);  // lanes 48-63: dup, unstored
        float (*wsm)[NCG][16] = (float (*)[NCG][16])scratch;
        for (int fc = 0; fc < 4; ++fc) {
            const int fbase = wave * 64 + fc * 16;
            for (int idx = lane; idx < NCG * 16; idx += 64) {
                const int c = idx >> 4, k = idx & 15;
                wsm[wave][c][k] = lin_w[c * NF + fbase + k];
            }
            __syncthreads();
            float xv[16];
            #pragma unroll
            for (int k = 0; k < 16; ++k) xv[k] = Xsm[fbase + k][kk];
            #pragma unroll
            for (int c = 0; c < NCG; ++c) {
                const float4* wr = (const float4*)(&wsm[wave][c][0]);  // 64B rows
                const float4 w0 = wr[0], w1 = wr[1], w2 = wr[2], w3 = wr[3];
                acc[c] += w0.x*xv[0]  + w0.y*xv[1]  + w0.z*xv[2]  + w0.w*xv[3]
                        + w1.x*xv[4]  + w1.y*xv[5]  + w1.z*xv[6]  + w1.w*xv[7]
                        + w2.x*xv[8]  + w2.y*xv[9]  + w2.z*xv[10] + w2.w*xv[11]
                        + w3.x*xv[12] + w3.y*xv[13] + w3.z*xv[14] + w3.w*xv[15];
            }
            __syncthreads();
        }
    }

    // ---- 3-round cross-wave reduce (single 66x64 buffer) ----
    {
        float (*red)[64] = (float (*)[64])scratch;
        if (wave == 3) {
            #pragma unroll
            for (int c = 0; c < NCG; ++c) red[c][lane] = acc[c];
        }
        __syncthreads();
        if (wave == 1) {
            #pragma unroll
            for (int c = 0; c < NCG; ++c) acc[c] += red[c][lane];
        }
        __syncthreads();
        if (wave == 2) {
            #pragma unroll
            for (int c = 0; c < NCG; ++c) red[c][lane] = acc[c];
        }
        __syncthreads();
        if (wave == 0) {
            #pragma unroll
            for (int c = 0; c < NCG; ++c) acc[c] += red[c][lane];
        }
        __syncthreads();
        if (wave == 1) {
            #pragma unroll
            for (int c = 0; c < NCG; ++c) red[c][lane] = acc[c];
        }
        __syncthreads();
        if (wave == 0) {
            #pragma unroll
            for (int c = 0; c < NCG; ++c) acc[c] += red[c][lane] + lin_b[c];
            // softmax over 66, keep 64
            float m = -INFINITY;
            #pragma unroll
            for (int c = 0; c < NCG; ++c) m = fmaxf(m, acc[c]);
            float s = 0.0f;
            #pragma unroll
            for (int c = 0; c < NCG; ++c) { acc[c] = __expf(acc[c] - m); s += acc[c]; }
            const int t = t0 + lane;
            const float sc = (t < NT) ? (1.0f / s) : 0.0f;   // zero padded t's
            if (lane < TCH) {
                #pragma unroll
                for (int c = 0; c < NC; ++c) Asm[c][lane] = acc[c] * sc;
            }
        }
        __syncthreads();
    }

    // ---- 8x8 aggregation over the 48-t chunk (asum folded in) ----
    {
        float ag[8][8], as[8];
        #pragma unroll
        for (int i = 0; i < 8; ++i) {
            as[i] = 0.0f;
            #pragma unroll
            for (int j = 0; j < 8; ++j) ag[i][j] = 0.0f;
        }
        const int cb = (tid >> 5) * 8;   // 8 c's per thread-group
        const int fl = tid & 31;         // f = fl + 32j

        #pragma unroll 4
        for (int k = 0; k < TCH; ++k) {
            float av[8], xv[8];
            #pragma unroll
            for (int i = 0; i < 8; ++i) av[i] = Asm[cb + i][k];     // broadcast
            #pragma unroll
            for (int j = 0; j < 8; ++j) xv[j] = Xsm[fl + 32 * j][k]; // stride 49: conflict-free
            #pragma unroll
            for (int i = 0; i < 8; ++i) {
                as[i] += av[i];
                #pragma unroll
                for (int j = 0; j < 8; ++j) ag[i][j] += av[i] * xv[j];
            }
        }

        #pragma unroll
        for (int i = 0; i < 8; ++i) {
            float* op = partial + ((size_t)((chunk * NU + u) * NC + cb + i)) * NF;
            #pragma unroll
            for (int j = 0; j < 8; ++j) op[fl + 32 * j] = ag[i][j];
        }
        if (fl == 0) {
            #pragma unroll
            for (int i = 0; i < 8; ++i)
                asum_part[(chunk * NU + u) * NC + cb + i] = as[i];
        }
    }
}

// ---------------- KB: reduce partials + intra-normalize ----------------
__global__ __launch_bounds__(256) void kb_norm(
        const float* __restrict__ asum_part, const float* __restrict__ partial,
        const float* __restrict__ centroids, float* __restrict__ compn,
        float* __restrict__ rowsq) {
    const int c = blockIdx.x, u = blockIdx.y;
    const int tid = threadIdx.x;
    __shared__ float sbuf[4];

    float asum = 0.0f;                   // uniform -> scalar loads
    #pragma unroll
    for (int ch = 0; ch < NCHUNK; ++ch)
        asum += asum_part[(ch * NU + u) * NC + c];

    float val = 0.0f;
    #pragma unroll
    for (int ch = 0; ch < NCHUNK; ++ch)
        val += partial[((size_t)((ch * NU + u) * NC + c)) * NF + tid];
    val -= asum * centroids[c * NF + tid];

    const float ss = blk_reduce_sum(val * val, sbuf);
    const float d  = fmaxf(sqrtf(ss), EPSN);
    compn[((size_t)(u * NC + c)) * NF + tid] = val / d;
    if (tid == 0) rowsq[u * NC + c] = ss / (d * d);
}

// ---------------- KC: global normalize ----------------
__global__ __launch_bounds__(256) void kc_scale(
        const float* __restrict__ compn, const float* __restrict__ rowsq,
        float* __restrict__ out) {
    const int u = blockIdx.y, sl = blockIdx.x;
    const int tid = threadIdx.x;
    float g = 0.0f;                      // uniform -> scalar loads
    #pragma unroll
    for (int c = 0; c < NC; ++c) g += rowsq[u * NC + c];
    const float inv = 1.0f / fmaxf(sqrtf(g), EPSN);
    const int base = u * (NC * NF) + sl * 1024 + tid * 4;
    float4 v = *(const float4*)(compn + base);
    v.x *= inv; v.y *= inv; v.z *= inv; v.w *= inv;
    *(float4*)(out + base) = v;
}

// ---------------- launcher ----------------
extern "C" void kernel_launch(void* const* d_in, const int* in_sizes, int n_in,
                              void* d_out, int out_size, void* d_ws, size_t ws_size,
                              hipStream_t stream) {
    (void)in_sizes; (void)n_in; (void)out_size; (void)ws_size;
    const float* x         = (const float*)d_in[0];
    const float* centroids = (const float*)d_in[1];
    const float* lin_w     = (const float*)d_in[2];
    const float* lin_b     = (const float*)d_in[3];
    float* out = (float*)d_out;

    float* ws        = (float*)d_ws;
    float* partial   = ws;                                        // 32*16*64*256 = 8,388,608 f
    float* asum_part = partial + (size_t)NCHUNK * NU * NC * NF;   // 32*16*64 = 32,768 f
    float* compn     = asum_part + NCHUNK * NU * NC;              // 262,144 f
    float* rowsq     = compn + (size_t)NU * NC * NF;              // 1,024 f (~34.7 MB)

    dim3 blk(256);
    hipLaunchKernelGGL(ka_fused, dim3(NCHUNK, NU), blk, 0, stream,
                       x, lin_w, lin_b, partial, asum_part);
    hipLaunchKernelGGL(kb_norm,  dim3(NC, NU), blk, 0, stream,
                       asum_part, partial, centroids, compn, rowsq);
    hipLaunchKernelGGL(kc_scale, dim3(16, NU), blk, 0, stream,
                       compn, rowsq, out);
}